// Round 3
// baseline (68.994 us; speedup 1.0000x reference)
//
#include <hip/hip_runtime.h>

#define NEG_INF (-1e30f)

static constexpr int Bn = 64;
static constexpr int Sn = 512;
static constexpr int Hn = 768;
static constexpr int Tn = 9;
static constexpr int KC = 32;      // chunks over steps 1..511
static constexpr int CL = 16;      // chunk length
static constexpr int PSTRIDE = 108; // 9 cols * 12 (padded rows, 16B aligned)

__device__ __forceinline__ float dot4(float4 a, float4 b) {
    return a.x * b.x + a.y * b.y + a.z * b.z + a.w * b.w;
}

// K1: emissions GEMM, BW-shaped. One wave per row-PAIR, W in registers,
// software prefetch of next pair's loads before current pair's compute.
__global__ __launch_bounds__(256) void emis_kernel(const float* __restrict__ emb,
        const float* __restrict__ Wm, const float* __restrict__ bias,
        float* __restrict__ em) {
    const int lane = threadIdx.x & 63;
    const int gw = (blockIdx.x * 256 + threadIdx.x) >> 6;
    const int nw = (gridDim.x * 256) >> 6;
    const int NP = (Bn * Sn) >> 1;   // 16384 row pairs

    float4 w[Tn][3];
#pragma unroll
    for (int t = 0; t < Tn; ++t) {
        const float4* w4 = (const float4*)(Wm + t * Hn);
#pragma unroll
        for (int i = 0; i < 3; ++i) w[t][i] = w4[lane + (i << 6)];
    }
    float bb[Tn];
#pragma unroll
    for (int t = 0; t < Tn; ++t) bb[t] = bias[t];

    const int sub = (lane < 9) ? lane : (lane - 9);

    float4 cA0, cA1, cA2, cB0, cB1, cB2;
    int p = gw;
    if (p < NP) {
        const float4* a4 = (const float4*)(emb + (size_t)(2 * p) * Hn);
        cA0 = a4[lane]; cA1 = a4[lane + 64]; cA2 = a4[lane + 128];
        cB0 = a4[lane + 192]; cB1 = a4[lane + 256]; cB2 = a4[lane + 320];
    }
    while (p < NP) {
        const int pn = p + nw;
        float4 nA0, nA1, nA2, nB0, nB1, nB2;
        if (pn < NP) {   // prefetch next pair — stays in flight across compute
            const float4* a4 = (const float4*)(emb + (size_t)(2 * pn) * Hn);
            nA0 = a4[lane]; nA1 = a4[lane + 64]; nA2 = a4[lane + 128];
            nB0 = a4[lane + 192]; nB1 = a4[lane + 256]; nB2 = a4[lane + 320];
        }
        float accA[Tn], accB[Tn];
#pragma unroll
        for (int t = 0; t < Tn; ++t) {
            accA[t] = dot4(cA0, w[t][0]) + dot4(cA1, w[t][1]) + dot4(cA2, w[t][2]);
            accB[t] = dot4(cB0, w[t][0]) + dot4(cB1, w[t][1]) + dot4(cB2, w[t][2]);
        }
#pragma unroll
        for (int off = 32; off; off >>= 1) {
#pragma unroll
            for (int t = 0; t < Tn; ++t) {
                accA[t] += __shfl_xor(accA[t], off);
                accB[t] += __shfl_xor(accB[t], off);
            }
        }
        float outv = 0.0f;
#pragma unroll
        for (int t = 0; t < Tn; ++t) {
            float va = fmaxf(accA[t] + bb[t], 0.0f);
            float vb = fmaxf(accB[t] + bb[t], 0.0f);
            float sel = (lane < 9) ? va : vb;
            outv = (sub == t) ? sel : outv;
        }
        if (lane < 18) em[(size_t)(2 * p) * Tn + lane] = outv;
        p = pn;
        cA0 = nA0; cA1 = nA1; cA2 = nA2;
        cB0 = nB0; cB1 = nB1; cB2 = nB2;
    }
}

// K2: per (batch, chunk): 9x9 log-semiring chunk matrix + partial numerator.
// Reads the small em array (L2-resident). Block = 128 threads (2 waves).
__global__ __launch_bounds__(128) void chunk_kernel(const float* __restrict__ em,
        const float* __restrict__ trans, const int* __restrict__ labels,
        const int* __restrict__ mask, float* __restrict__ chunkP,
        float* __restrict__ auxN, int* __restrict__ auxC) {
    const int bk = blockIdx.x;
    const int b  = bk >> 5;
    const int k  = bk & 31;
    const int t0 = 1 + k * CL;
    const int tid  = threadIdx.x;
    const int w    = tid >> 6;
    const int lane = tid & 63;

    __shared__ float em_s[CL][Tn];
    __shared__ int   on_s[CL];
    __shared__ float tr_s[81];

    if (tid < 81) tr_s[tid] = trans[tid];

    int myLab = 0, myLabP = 0, myOn = 0;
    if (tid < CL) {
        int t = t0 + tid;
        if (t < Sn) {
            int lb = labels[b * Sn + t];
            int lp = labels[b * Sn + t - 1];
            int mm = mask[b * Sn + t];
            myOn  = (mm != 0) && (lb != -100);
            myLab = (lb == -100) ? 0 : lb;
            myLabP = (lp == -100) ? 0 : lp;
        }
        on_s[tid] = myOn;
    }
    {
        const int nst = (Sn - t0 < CL) ? (Sn - t0) : CL;
        const float* src = em + (size_t)(b * Sn + t0) * Tn;
        for (int u = tid; u < nst * Tn; u += 128) ((float*)em_s)[u] = src[u];
    }
    __syncthreads();

    // partial numerator + mask count (wave 0, lanes 0..15)
    float nump = 0.0f;
    int cnt = 0;
    if (tid < CL && myOn) {
        nump = em_s[tid][myLab] + tr_s[myLabP * Tn + myLab];
        cnt = 1;
    }
    if (w == 0) {
#pragma unroll
        for (int off = 8; off; off >>= 1) {
            nump += __shfl_xor(nump, off);
            cnt  += __shfl_xor(cnt, off);
        }
        if (lane == 0) { auxN[bk] = nump; auxC[bk] = cnt; }
    }

    // chunk matrix: 9 basis row-vectors in-register.
    // wave 0: rows 0..4 (lanes 0..44); wave 1: rows 5..8 (lanes 0..35)
    const int v  = lane / 9;
    const int jj = lane - v * 9;
    const bool act = lane < ((w == 0) ? 45 : 36);
    const int rid = (w == 0) ? v : (5 + v);

    float c[Tn];
#pragma unroll
    for (int kk = 0; kk < Tn; ++kk) c[kk] = tr_s[kk * Tn + jj];

    float pv = (act && rid == jj) ? 0.0f : NEG_INF;

    for (int u = 0; u < CL; ++u) {
        if (!on_s[u]) continue;   // block-uniform
        float x[Tn];
#pragma unroll
        for (int kk = 0; kk < Tn; ++kk) {
            float a = __shfl(pv, (v * Tn + kk) & 63);
            x[kk] = a + c[kk];
        }
        float mx = x[0];
#pragma unroll
        for (int kk = 1; kk < Tn; ++kk) mx = fmaxf(mx, x[kk]);
        float s = 0.0f;
#pragma unroll
        for (int kk = 0; kk < Tn; ++kk) s += __expf(x[kk] - mx);
        float nv = mx + __logf(s) + em_s[u][jj];
        pv = act ? nv : pv;
    }
    if (act) chunkP[(size_t)bk * PSTRIDE + jj * 12 + rid] = pv;
}

// K3: per batch (one wave): alpha chain over 32 chunk matrices + denom + nll
__global__ __launch_bounds__(64) void combine_kernel(const float* __restrict__ em,
        const float* __restrict__ startT, const float* __restrict__ endT,
        const int* __restrict__ labels, const int* __restrict__ mask,
        const float* __restrict__ chunkP, const float* __restrict__ auxN,
        const int* __restrict__ auxC, float* __restrict__ nll) {
    const int b = blockIdx.x;
    const int lane = threadIdx.x;

    float em0 = (lane < Tn) ? em[(size_t)b * Sn * Tn + lane] : NEG_INF;
    float alpha = (lane < Tn) ? (startT[lane] + em0) : NEG_INF;

    int lab0r = labels[b * Sn];
    int lab0 = (lab0r == -100) ? 0 : lab0r;
    float first = startT[lab0] + __shfl(em0, lab0);

    float numP = (lane < KC) ? auxN[b * KC + lane] : 0.0f;
    int   cntP = (lane < KC) ? auxC[b * KC + lane] : 0;
#pragma unroll
    for (int off = 32; off; off >>= 1) {
        numP += __shfl_xor(numP, off);
        cntP += __shfl_xor(cntP, off);
    }
    int m0 = ((mask[b * Sn] != 0) && (lab0r != -100)) ? 1 : 0;
    int cntTot = cntP + m0;
    int lastIdx = cntTot - 1;
    if (lastIdx < 0) lastIdx = 0;
    int lastLab = labels[b * Sn + lastIdx];
    lastLab = (lastLab == -100) ? 0 : lastLab;
    float num = first + numP + endT[lastLab];

    const float* Pb = chunkP + (size_t)b * KC * PSTRIDE;
    float4 p0 = make_float4(0, 0, 0, 0), p1 = p0, p2 = p0;
    if (lane < Tn) {
        const float4* pp = (const float4*)(Pb + lane * 12);
        p0 = pp[0]; p1 = pp[1]; p2 = pp[2];
    }
    for (int k = 0; k < KC; ++k) {
        float4 q0 = p0, q1 = p1, q2 = p2;
        if (k + 1 < KC && lane < Tn) {
            const float4* pp = (const float4*)(Pb + (size_t)(k + 1) * PSTRIDE + lane * 12);
            p0 = pp[0]; p1 = pp[1]; p2 = pp[2];
        }
        float av[Tn];
#pragma unroll
        for (int i = 0; i < Tn; ++i) av[i] = __shfl(alpha, i);
        float x[Tn];
        x[0] = av[0] + q0.x; x[1] = av[1] + q0.y; x[2] = av[2] + q0.z;
        x[3] = av[3] + q0.w; x[4] = av[4] + q1.x; x[5] = av[5] + q1.y;
        x[6] = av[6] + q1.z; x[7] = av[7] + q1.w; x[8] = av[8] + q2.x;
        float mx = x[0];
#pragma unroll
        for (int i = 1; i < Tn; ++i) mx = fmaxf(mx, x[i]);
        float s = 0.0f;
#pragma unroll
        for (int i = 0; i < Tn; ++i) s += __expf(x[i] - mx);
        float na = mx + __logf(s);
        alpha = (lane < Tn) ? na : NEG_INF;
    }

    float z = (lane < Tn) ? (alpha + endT[lane]) : NEG_INF;
    float mx = z;
#pragma unroll
    for (int off = 32; off; off >>= 1) mx = fmaxf(mx, __shfl_xor(mx, off));
    float s = __expf(z - mx);
#pragma unroll
    for (int off = 32; off; off >>= 1) s += __shfl_xor(s, off);
    float denom = mx + __logf(s);

    if (lane == 0) nll[b] = denom - num;
}

__global__ __launch_bounds__(64) void mean_kernel(const float* __restrict__ nll,
        float* __restrict__ out) {
    float v = nll[threadIdx.x];
#pragma unroll
    for (int off = 32; off; off >>= 1) v += __shfl_xor(v, off);
    if (threadIdx.x == 0) out[0] = v * (1.0f / 64.0f);
}

extern "C" void kernel_launch(void* const* d_in, const int* in_sizes, int n_in,
                              void* d_out, int out_size, void* d_ws, size_t ws_size,
                              hipStream_t stream) {
    const float* emb    = (const float*)d_in[0];
    const float* Wm     = (const float*)d_in[1];
    const float* bias   = (const float*)d_in[2];
    const float* startT = (const float*)d_in[3];
    const float* trans  = (const float*)d_in[4];
    const float* endT   = (const float*)d_in[5];
    const int*   labels = (const int*)d_in[6];
    const int*   mask   = (const int*)d_in[7];

    float* em     = (float*)d_ws;                        // B*S*T floats
    float* chunkP = em + (size_t)Bn * Sn * Tn;           // B*KC*108 floats
    float* auxN   = chunkP + (size_t)Bn * KC * PSTRIDE;  // B*KC floats
    int*   auxC   = (int*)(auxN + (size_t)Bn * KC);      // B*KC ints
    float* nll    = (float*)(auxC + (size_t)Bn * KC);    // B floats
    float* out    = (float*)d_out;

    emis_kernel<<<768, 256, 0, stream>>>(emb, Wm, bias, em);
    chunk_kernel<<<Bn * KC, 128, 0, stream>>>(em, trans, labels, mask,
                                              chunkP, auxN, auxC);
    combine_kernel<<<Bn, 64, 0, stream>>>(em, startT, endT, labels, mask,
                                          chunkP, auxN, auxC, nll);
    mean_kernel<<<1, 64, 0, stream>>>(nll, out);
}

// Round 4
// 60.298 us; speedup vs baseline: 1.1442x; 1.1442x over previous
//
#include <hip/hip_runtime.h>

#define NEG_INF (-1e30f)

static constexpr int Bn = 64;
static constexpr int Sn = 512;
static constexpr int Hn = 768;
static constexpr int Tn = 9;
static constexpr int KC = 32;      // chunks over steps 1..511
static constexpr int CL = 16;      // chunk length
static constexpr int PSTRIDE = 108; // 9 cols * 12 (padded rows, 16B aligned)

__device__ __forceinline__ float dot4(float4 a, float4 b) {
    return a.x * b.x + a.y * b.y + a.z * b.z + a.w * b.w;
}

// K1: emissions GEMM. Block = 512 threads = 8 waves, owns 64 consecutive rows.
// Wave w handles H-segment [96w, 96w+96); lane L owns row blk*64+L privately
// (9 accumulators, no cross-lane reduce). W read via wave-uniform scalar loads.
// Per-block LDS reduce over the 8 segments, then one coalesced store.
__global__ __launch_bounds__(512) void emis_kernel(const float* __restrict__ emb,
        const float* __restrict__ Wm, const float* __restrict__ bias,
        float* __restrict__ em) {
    const int blk  = blockIdx.x;       // 512 blocks, 64 rows each
    const int tid  = threadIdx.x;
    const int lane = tid & 63;
    const int seg  = __builtin_amdgcn_readfirstlane(tid >> 6);   // 0..7, SGPR
    const int row  = blk * 64 + lane;

    __shared__ float part[8][64][Tn];   // 18 KiB

    const float4* e4 = (const float4*)emb + (size_t)row * 192 + seg * 24;
    const float4* w4 = (const float4*)Wm;   // [t*192 + h4]

    float acc[Tn];
#pragma unroll
    for (int t = 0; t < Tn; ++t) acc[t] = 0.0f;

#pragma unroll 4
    for (int i = 0; i < 24; ++i) {
        float4 e = e4[i];
#pragma unroll
        for (int t = 0; t < Tn; ++t) {
            float4 wt = w4[t * 192 + seg * 24 + i];   // uniform -> s_load
            acc[t] += dot4(e, wt);
        }
    }
#pragma unroll
    for (int t = 0; t < Tn; ++t) part[seg][lane][t] = acc[t];
    __syncthreads();

    for (int o = tid; o < 64 * Tn; o += 512) {
        int r = o / Tn, t = o - r * Tn;
        float s = 0.0f;
#pragma unroll
        for (int sg = 0; sg < 8; ++sg) s += part[sg][r][t];
        em[(size_t)blk * (64 * Tn) + o] = fmaxf(s + bias[t], 0.0f);
    }
}

// K2: per (batch, chunk): 9x9 log-semiring chunk matrix + partial numerator.
// Reads the small em array (L2-resident). Block = 128 threads (2 waves).
__global__ __launch_bounds__(128) void chunk_kernel(const float* __restrict__ em,
        const float* __restrict__ trans, const int* __restrict__ labels,
        const int* __restrict__ mask, float* __restrict__ chunkP,
        float* __restrict__ auxN, int* __restrict__ auxC) {
    const int bk = blockIdx.x;
    const int b  = bk >> 5;
    const int k  = bk & 31;
    const int t0 = 1 + k * CL;
    const int tid  = threadIdx.x;
    const int w    = tid >> 6;
    const int lane = tid & 63;

    __shared__ float em_s[CL][Tn];
    __shared__ int   on_s[CL];
    __shared__ float tr_s[81];

    if (tid < 81) tr_s[tid] = trans[tid];

    int myLab = 0, myLabP = 0, myOn = 0;
    if (tid < CL) {
        int t = t0 + tid;
        if (t < Sn) {
            int lb = labels[b * Sn + t];
            int lp = labels[b * Sn + t - 1];
            int mm = mask[b * Sn + t];
            myOn  = (mm != 0) && (lb != -100);
            myLab = (lb == -100) ? 0 : lb;
            myLabP = (lp == -100) ? 0 : lp;
        }
        on_s[tid] = myOn;
    }
    {
        const int nst = (Sn - t0 < CL) ? (Sn - t0) : CL;
        const float* src = em + (size_t)(b * Sn + t0) * Tn;
        for (int u = tid; u < nst * Tn; u += 128) ((float*)em_s)[u] = src[u];
    }
    __syncthreads();

    // partial numerator + mask count (wave 0, lanes 0..15)
    float nump = 0.0f;
    int cnt = 0;
    if (tid < CL && myOn) {
        nump = em_s[tid][myLab] + tr_s[myLabP * Tn + myLab];
        cnt = 1;
    }
    if (w == 0) {
#pragma unroll
        for (int off = 8; off; off >>= 1) {
            nump += __shfl_xor(nump, off);
            cnt  += __shfl_xor(cnt, off);
        }
        if (lane == 0) { auxN[bk] = nump; auxC[bk] = cnt; }
    }

    // chunk matrix: 9 basis row-vectors in-register.
    // wave 0: rows 0..4 (lanes 0..44); wave 1: rows 5..8 (lanes 0..35)
    const int v  = lane / 9;
    const int jj = lane - v * 9;
    const bool act = lane < ((w == 0) ? 45 : 36);
    const int rid = (w == 0) ? v : (5 + v);

    float c[Tn];
#pragma unroll
    for (int kk = 0; kk < Tn; ++kk) c[kk] = tr_s[kk * Tn + jj];

    float pv = (act && rid == jj) ? 0.0f : NEG_INF;

    for (int u = 0; u < CL; ++u) {
        if (!on_s[u]) continue;   // block-uniform
        float x[Tn];
#pragma unroll
        for (int kk = 0; kk < Tn; ++kk) {
            float a = __shfl(pv, (v * Tn + kk) & 63);
            x[kk] = a + c[kk];
        }
        float mx = x[0];
#pragma unroll
        for (int kk = 1; kk < Tn; ++kk) mx = fmaxf(mx, x[kk]);
        float s = 0.0f;
#pragma unroll
        for (int kk = 0; kk < Tn; ++kk) s += __expf(x[kk] - mx);
        float nv = mx + __logf(s) + em_s[u][jj];
        pv = act ? nv : pv;
    }
    if (act) chunkP[(size_t)bk * PSTRIDE + jj * 12 + rid] = pv;
}

// K3: per batch (one wave): alpha chain over 32 chunk matrices + denom + nll
__global__ __launch_bounds__(64) void combine_kernel(const float* __restrict__ em,
        const float* __restrict__ startT, const float* __restrict__ endT,
        const int* __restrict__ labels, const int* __restrict__ mask,
        const float* __restrict__ chunkP, const float* __restrict__ auxN,
        const int* __restrict__ auxC, float* __restrict__ nll) {
    const int b = blockIdx.x;
    const int lane = threadIdx.x;

    float em0 = (lane < Tn) ? em[(size_t)b * Sn * Tn + lane] : NEG_INF;
    float alpha = (lane < Tn) ? (startT[lane] + em0) : NEG_INF;

    int lab0r = labels[b * Sn];
    int lab0 = (lab0r == -100) ? 0 : lab0r;
    float first = startT[lab0] + __shfl(em0, lab0);

    float numP = (lane < KC) ? auxN[b * KC + lane] : 0.0f;
    int   cntP = (lane < KC) ? auxC[b * KC + lane] : 0;
#pragma unroll
    for (int off = 32; off; off >>= 1) {
        numP += __shfl_xor(numP, off);
        cntP += __shfl_xor(cntP, off);
    }
    int m0 = ((mask[b * Sn] != 0) && (lab0r != -100)) ? 1 : 0;
    int cntTot = cntP + m0;
    int lastIdx = cntTot - 1;
    if (lastIdx < 0) lastIdx = 0;
    int lastLab = labels[b * Sn + lastIdx];
    lastLab = (lastLab == -100) ? 0 : lastLab;
    float num = first + numP + endT[lastLab];

    const float* Pb = chunkP + (size_t)b * KC * PSTRIDE;
    float4 p0 = make_float4(0, 0, 0, 0), p1 = p0, p2 = p0;
    if (lane < Tn) {
        const float4* pp = (const float4*)(Pb + lane * 12);
        p0 = pp[0]; p1 = pp[1]; p2 = pp[2];
    }
    for (int k = 0; k < KC; ++k) {
        float4 q0 = p0, q1 = p1, q2 = p2;
        if (k + 1 < KC && lane < Tn) {
            const float4* pp = (const float4*)(Pb + (size_t)(k + 1) * PSTRIDE + lane * 12);
            p0 = pp[0]; p1 = pp[1]; p2 = pp[2];
        }
        float av[Tn];
#pragma unroll
        for (int i = 0; i < Tn; ++i) av[i] = __shfl(alpha, i);
        float x[Tn];
        x[0] = av[0] + q0.x; x[1] = av[1] + q0.y; x[2] = av[2] + q0.z;
        x[3] = av[3] + q0.w; x[4] = av[4] + q1.x; x[5] = av[5] + q1.y;
        x[6] = av[6] + q1.z; x[7] = av[7] + q1.w; x[8] = av[8] + q2.x;
        float mx = x[0];
#pragma unroll
        for (int i = 1; i < Tn; ++i) mx = fmaxf(mx, x[i]);
        float s = 0.0f;
#pragma unroll
        for (int i = 0; i < Tn; ++i) s += __expf(x[i] - mx);
        float na = mx + __logf(s);
        alpha = (lane < Tn) ? na : NEG_INF;
    }

    float z = (lane < Tn) ? (alpha + endT[lane]) : NEG_INF;
    float mx = z;
#pragma unroll
    for (int off = 32; off; off >>= 1) mx = fmaxf(mx, __shfl_xor(mx, off));
    float s = __expf(z - mx);
#pragma unroll
    for (int off = 32; off; off >>= 1) s += __shfl_xor(s, off);
    float denom = mx + __logf(s);

    if (lane == 0) nll[b] = denom - num;
}

__global__ __launch_bounds__(64) void mean_kernel(const float* __restrict__ nll,
        float* __restrict__ out) {
    float v = nll[threadIdx.x];
#pragma unroll
    for (int off = 32; off; off >>= 1) v += __shfl_xor(v, off);
    if (threadIdx.x == 0) out[0] = v * (1.0f / 64.0f);
}

extern "C" void kernel_launch(void* const* d_in, const int* in_sizes, int n_in,
                              void* d_out, int out_size, void* d_ws, size_t ws_size,
                              hipStream_t stream) {
    const float* emb    = (const float*)d_in[0];
    const float* Wm     = (const float*)d_in[1];
    const float* bias   = (const float*)d_in[2];
    const float* startT = (const float*)d_in[3];
    const float* trans  = (const float*)d_in[4];
    const float* endT   = (const float*)d_in[5];
    const int*   labels = (const int*)d_in[6];
    const int*   mask   = (const int*)d_in[7];

    float* em     = (float*)d_ws;                        // B*S*T floats
    float* chunkP = em + (size_t)Bn * Sn * Tn;           // B*KC*108 floats
    float* auxN   = chunkP + (size_t)Bn * KC * PSTRIDE;  // B*KC floats
    int*   auxC   = (int*)(auxN + (size_t)Bn * KC);      // B*KC ints
    float* nll    = (float*)(auxC + (size_t)Bn * KC);    // B floats
    float* out    = (float*)d_out;

    emis_kernel<<<Bn * Sn / 64, 512, 0, stream>>>(emb, Wm, bias, em);
    chunk_kernel<<<Bn * KC, 128, 0, stream>>>(em, trans, labels, mask,
                                              chunkP, auxN, auxC);
    combine_kernel<<<Bn, 64, 0, stream>>>(em, startT, endT, labels, mask,
                                          chunkP, auxN, auxC, nll);
    mean_kernel<<<1, 64, 0, stream>>>(nll, out);
}